// Round 14
// baseline (6941.851 us; speedup 1.0000x reference)
//
#include <hip/hip_runtime.h>

#define DH 30
#define SLOPE 0.01f

typedef float v2 __attribute__((ext_vector_type(2)));
#define SB() __builtin_amdgcn_sched_barrier(0)

// LDS layout (floats): W1[9][32]@0, W2[30][32]@288, W3[30][32]@1248,
// b1[32]@2208, b2[32]@2240, b3[32]@2272, W4[32]@2304, b4@2336. Pads zero.
#define W1_OFF 0
#define W2_OFF 288
#define W3_OFF 1248
#define B1_OFF 2208
#define B2_OFF 2240
#define B3_OFF 2272
#define W4_OFF 2304
#define B4_OFF 2336

// R13 model: kernel is LDS-pipe-throughput bound (per-CU shared pipe,
// every wave re-broadcasts the same 2.3k weights). Fix: 2 samples/thread
// -> each ds_read feeds 2 fma chains -> per-CU LDS ops halve. v4 row loads
// force b128 merges. VGPR cap 176 just above ~165 live set (R4 vs R13:
// cap-above-live prevents allocator balloon; cap-below-live spills).
__global__ __launch_bounds__(256) __attribute__((amdgpu_num_vgpr(176)))
void mlp_fwdbwd(
    const float4* __restrict__ pe,
    const float*  __restrict__ q,
    const float4* __restrict__ s,
    const float* __restrict__ W1, const float* __restrict__ b1,
    const float* __restrict__ W2, const float* __restrict__ b2,
    const float* __restrict__ W3, const float* __restrict__ b3,
    const float* __restrict__ W4, const float* __restrict__ b4,
    float* __restrict__ dout, int n)
{
    __shared__ float lw[2368];
    const int tid = threadIdx.x;
    for (int idx = tid; idx < 2368; idx += 256) {
        float v = 0.f;
        if (idx < 288)        { int tt = idx,        r = tt >> 5, c = tt & 31; v = (c < DH) ? W1[r * DH + c] : 0.f; }
        else if (idx < 1248)  { int tt = idx - 288,  r = tt >> 5, c = tt & 31; v = (c < DH) ? W2[r * DH + c] : 0.f; }
        else if (idx < 2208)  { int tt = idx - 1248, r = tt >> 5, c = tt & 31; v = (c < DH) ? W3[r * DH + c] : 0.f; }
        else if (idx < 2240)  { int c = idx - 2208; v = (c < DH) ? b1[c] : 0.f; }
        else if (idx < 2272)  { int c = idx - 2240; v = (c < DH) ? b2[c] : 0.f; }
        else if (idx < 2304)  { int c = idx - 2272; v = (c < DH) ? b3[c] : 0.f; }
        else if (idx < 2336)  { int c = idx - 2304; v = (c < DH) ? W4[c] : 0.f; }
        else if (idx == 2336) { v = b4[0]; }
        lw[idx] = v;
    }
    __syncthreads();

    const int t = blockIdx.x * 256 + tid;
    const int half = (n + 1) >> 1;
    if (t >= half) return;
    const bool has2 = (t + half) < n;
    const int i0 = t;
    const int i1 = has2 ? (t + half) : t;   // safe addr; stores guarded

    float x0[9], x1[9];
    {
        const float4 a = pe[i0]; const float4 b = s[i0]; const float qq = q[i0];
        x0[0]=a.x; x0[1]=a.y; x0[2]=a.z; x0[3]=a.w; x0[4]=qq;
        x0[5]=b.x; x0[6]=b.y; x0[7]=b.z; x0[8]=b.w;
    }
    {
        const float4 a = pe[i1]; const float4 b = s[i1]; const float qq = q[i1];
        x1[0]=a.x; x1[1]=a.y; x1[2]=a.z; x1[3]=a.w; x1[4]=qq;
        x1[5]=b.x; x1[6]=b.y; x1[7]=b.z; x1[8]=b.w;
    }

    v2 a0[15], a1[15], h0[15], h1[15];
    unsigned m1a=0, m1b=0, m2a=0, m2b=0, m3a=0, m3b=0;
    const v2 slope2 = { SLOPE, SLOPE };

    // row macro: 7x float4 + 1x float2 loads; per-v2 fma order identical to
    // the jj-ascending order of the passing R13 kernel (bit-identical fwd).
    #define ROW_FMA2(OFF, k, s0, s1)                                          \
    {                                                                         \
        const float4* Wr4 = reinterpret_cast<const float4*>(lw + OFF + (k)*32);\
        const v2*     Wr2 = reinterpret_cast<const v2*>(lw + OFF + (k)*32);   \
        _Pragma("unroll")                                                     \
        for (int j4 = 0; j4 < 7; ++j4) {                                      \
            const float4 w = Wr4[j4];                                         \
            const v2 wlo = { w.x, w.y };                                      \
            const v2 whi = { w.z, w.w };                                      \
            a0[2*j4]   = __builtin_elementwise_fma(s0, wlo, a0[2*j4]);        \
            a1[2*j4]   = __builtin_elementwise_fma(s1, wlo, a1[2*j4]);        \
            a0[2*j4+1] = __builtin_elementwise_fma(s0, whi, a0[2*j4+1]);      \
            a1[2*j4+1] = __builtin_elementwise_fma(s1, whi, a1[2*j4+1]);      \
        }                                                                     \
        const v2 wl = Wr2[14];                                                \
        a0[14] = __builtin_elementwise_fma(s0, wl, a0[14]);                   \
        a1[14] = __builtin_elementwise_fma(s1, wl, a1[14]);                   \
    }

    // ---- layer 1 ----
    #pragma unroll
    for (int jj = 0; jj < 15; ++jj) { a0[jj] = (v2){0.f,0.f}; a1[jj] = (v2){0.f,0.f}; }
    #pragma unroll
    for (int k = 0; k < 9; ++k) {
        const v2 xv0 = { x0[k], x0[k] };
        const v2 xv1 = { x1[k], x1[k] };
        ROW_FMA2(W1_OFF, k, xv0, xv1);
        SB();
    }
    {
        const v2* bv = reinterpret_cast<const v2*>(lw + B1_OFF);
        #pragma unroll
        for (int jj = 0; jj < 15; ++jj) {
            const v2 bb = bv[jj];
            const v2 z0 = a0[jj] + bb;
            const v2 z1 = a1[jj] + bb;
            if (z0.x > 0.f) m1a |= (1u << (2*jj));
            if (z0.y > 0.f) m1a |= (1u << (2*jj+1));
            if (z1.x > 0.f) m1b |= (1u << (2*jj));
            if (z1.y > 0.f) m1b |= (1u << (2*jj+1));
            h0[jj] = __builtin_elementwise_max(z0, z0 * slope2);  // bit-identical LeakyReLU
            h1[jj] = __builtin_elementwise_max(z1, z1 * slope2);
        }
    }
    SB();

    // ---- layer 2 ----
    #pragma unroll
    for (int jj = 0; jj < 15; ++jj) { a0[jj] = (v2){0.f,0.f}; a1[jj] = (v2){0.f,0.f}; }
    #pragma unroll
    for (int k = 0; k < DH; ++k) {
        const float hk0 = h0[k >> 1][k & 1];
        const float hk1 = h1[k >> 1][k & 1];
        const v2 hv0 = { hk0, hk0 };
        const v2 hv1 = { hk1, hk1 };
        ROW_FMA2(W2_OFF, k, hv0, hv1);
        SB();
    }
    {
        const v2* bv = reinterpret_cast<const v2*>(lw + B2_OFF);
        #pragma unroll
        for (int jj = 0; jj < 15; ++jj) {
            const v2 bb = bv[jj];
            const v2 z0 = a0[jj] + bb;
            const v2 z1 = a1[jj] + bb;
            if (z0.x > 0.f) m2a |= (1u << (2*jj));
            if (z0.y > 0.f) m2a |= (1u << (2*jj+1));
            if (z1.x > 0.f) m2b |= (1u << (2*jj));
            if (z1.y > 0.f) m2b |= (1u << (2*jj+1));
            h0[jj] = __builtin_elementwise_max(z0, z0 * slope2);
            h1[jj] = __builtin_elementwise_max(z1, z1 * slope2);
        }
    }
    SB();

    // ---- layer 3 ----
    #pragma unroll
    for (int jj = 0; jj < 15; ++jj) { a0[jj] = (v2){0.f,0.f}; a1[jj] = (v2){0.f,0.f}; }
    #pragma unroll
    for (int k = 0; k < DH; ++k) {
        const float hk0 = h0[k >> 1][k & 1];
        const float hk1 = h1[k >> 1][k & 1];
        const v2 hv0 = { hk0, hk0 };
        const v2 hv1 = { hk1, hk1 };
        ROW_FMA2(W3_OFF, k, hv0, hv1);
        SB();
    }
    // output dot: scalar, j ascending (bit-identical to R13)
    const float* b3p = lw + B3_OFF;
    const float* W4p = lw + W4_OFF;
    float out0 = 0.f, out1 = 0.f;
    #pragma unroll
    for (int j = 0; j < DH; ++j) {
        const float bb = b3p[j];
        const float w4 = W4p[j];
        const float z0 = a0[j >> 1][j & 1] + bb;
        const float z1 = a1[j >> 1][j & 1] + bb;
        if (z0 > 0.f) m3a |= (1u << j);
        if (z1 > 0.f) m3b |= (1u << j);
        const float hz0 = (z0 > 0.f) ? z0 : SLOPE * z0;
        const float hz1 = (z1 > 0.f) ? z1 : SLOPE * z1;
        out0 = fmaf(hz0, w4, out0);
        out1 = fmaf(hz1, w4, out1);
    }
    out0 += lw[B4_OFF];
    out1 += lw[B4_OFF];
    SB();

    // ---- backward (mask-driven; value-continuous) ----
    // reuse h0/h1 as g-buffers to bound registers
    v2 g30[15], g31[15];
    {
        const v2* w4v = reinterpret_cast<const v2*>(W4p);
        #pragma unroll
        for (int jj = 0; jj < 15; ++jj) {
            const v2 w = w4v[jj];
            g30[jj].x = ((m3a >> (2*jj))   & 1u) ? w.x : SLOPE * w.x;
            g30[jj].y = ((m3a >> (2*jj+1)) & 1u) ? w.y : SLOPE * w.y;
            g31[jj].x = ((m3b >> (2*jj))   & 1u) ? w.x : SLOPE * w.x;
            g31[jj].y = ((m3b >> (2*jj+1)) & 1u) ? w.y : SLOPE * w.y;
        }
    }
    #define ROW_DOT2(OFF, k, G0, G1, D0, D1)                                  \
    {                                                                         \
        const float4* Wr4 = reinterpret_cast<const float4*>(lw + OFF + (k)*32);\
        const v2*     Wr2 = reinterpret_cast<const v2*>(lw + OFF + (k)*32);   \
        v2 d0a = (v2){0.f,0.f}, d0b = (v2){0.f,0.f};                          \
        v2 d1a = (v2){0.f,0.f}, d1b = (v2){0.f,0.f};                          \
        _Pragma("unroll")                                                     \
        for (int j4 = 0; j4 < 7; ++j4) {                                      \
            const float4 w = Wr4[j4];                                         \
            const v2 wlo = { w.x, w.y };                                      \
            const v2 whi = { w.z, w.w };                                      \
            d0a = __builtin_elementwise_fma(G0[2*j4],   wlo, d0a);            \
            d0b = __builtin_elementwise_fma(G0[2*j4+1], whi, d0b);            \
            d1a = __builtin_elementwise_fma(G1[2*j4],   wlo, d1a);            \
            d1b = __builtin_elementwise_fma(G1[2*j4+1], whi, d1b);            \
        }                                                                     \
        const v2 wl = Wr2[14];                                                \
        d0a = __builtin_elementwise_fma(G0[14], wl, d0a);                     \
        d1a = __builtin_elementwise_fma(G1[14], wl, d1a);                     \
        D0 = (d0a.x + d0a.y) + (d0b.x + d0b.y);                               \
        D1 = (d1a.x + d1a.y) + (d1b.x + d1b.y);                               \
    }

    // g2 into h0/h1
    #pragma unroll
    for (int k = 0; k < DH; ++k) {
        float dot0, dot1;
        ROW_DOT2(W3_OFF, k, g30, g31, dot0, dot1);
        h0[k >> 1][k & 1] = ((m2a >> k) & 1u) ? dot0 : SLOPE * dot0;
        h1[k >> 1][k & 1] = ((m2b >> k) & 1u) ? dot1 : SLOPE * dot1;
        SB();
    }
    // g1 into g30/g31
    #pragma unroll
    for (int k = 0; k < DH; ++k) {
        float dot0, dot1;
        ROW_DOT2(W2_OFF, k, h0, h1, dot0, dot1);
        g30[k >> 1][k & 1] = ((m1a >> k) & 1u) ? dot0 : SLOPE * dot0;
        g31[k >> 1][k & 1] = ((m1b >> k) & 1u) ? dot1 : SLOPE * dot1;
        SB();
    }
    float gx0[9], gx1[9];
    #pragma unroll
    for (int k = 0; k < 9; ++k) {
        float dot0, dot1;
        ROW_DOT2(W1_OFF, k, g30, g31, dot0, dot1);
        gx0[k] = dot0;
        gx1[k] = dot1;
        SB();
    }

    // ---- stores: [out(N) | h_s(4N) | h_q(N) | h_pe(4N)] ----
    float4* hs  = reinterpret_cast<float4*>(dout + (size_t)n);
    float4* hpe = reinterpret_cast<float4*>(dout + (size_t)6 * n);

    dout[i0] = out0;
    hs[i0]   = make_float4(gx0[5], gx0[6], gx0[7], gx0[8]);
    dout[(size_t)5 * n + i0] = gx0[4];
    hpe[i0]  = make_float4(gx0[0], gx0[1], gx0[2], gx0[3]);
    if (has2) {
        dout[i1] = out1;
        hs[i1]   = make_float4(gx1[5], gx1[6], gx1[7], gx1[8]);
        dout[(size_t)5 * n + i1] = gx1[4];
        hpe[i1]  = make_float4(gx1[0], gx1[1], gx1[2], gx1[3]);
    }
}

extern "C" void kernel_launch(void* const* d_in, const int* in_sizes, int n_in,
                              void* d_out, int out_size, void* d_ws, size_t ws_size,
                              hipStream_t stream) {
    const int n = in_sizes[1];  // input_q has N elements
    const int half = (n + 1) >> 1;
    const int blocks = (half + 255) / 256;
    hipLaunchKernelGGL(mlp_fwdbwd, dim3(blocks), dim3(256), 0, stream,
        (const float4*)d_in[0], (const float*)d_in[1], (const float4*)d_in[2],
        (const float*)d_in[3], (const float*)d_in[4],
        (const float*)d_in[5], (const float*)d_in[6],
        (const float*)d_in[7], (const float*)d_in[8],
        (const float*)d_in[9], (const float*)d_in[10],
        (float*)d_out, n);
}

// Round 15
// 5896.055 us; speedup vs baseline: 1.1774x; 1.1774x over previous
//
#include <hip/hip_runtime.h>

#define DH 30
#define SLOPE 0.01f

typedef float v2 __attribute__((ext_vector_type(2)));

// LDS layout (floats): W1[9][32]@0, W2[30][32]@288, W3[30][32]@1248,
// b1[32]@2208, b2[32]@2240, b3[32]@2272, W4[32]@2304, b4@2336. Pads zero.
#define W1_OFF 0
#define W2_OFF 288
#define W3_OFF 1248
#define B1_OFF 2208
#define B2_OFF 2240
#define B3_OFF 2272
#define W4_OFF 2304
#define B4_OFF 2336

// R13 (152us) minus in-loop sched_barriers (they blocked ds_read/FMA overlap
// that LDS's counted lgkmcnt enables), plus float4 row reads (8 ds-ops/row
// vs 15). (256,6) caps VGPR at 85, just above the ~78 live set: the
// pressure-aware scheduler then hoists only a row or two ahead (R3: no cap
// -> 256+spills; R5/R10: cap below live set -> spills; R13: cap-above-live
// is the stable point). 1 sample/thread (R7/R14: 2-sample never fits).
__global__ __launch_bounds__(256, 6) void mlp_fwdbwd(
    const float4* __restrict__ pe,
    const float*  __restrict__ q,
    const float4* __restrict__ s,
    const float* __restrict__ W1, const float* __restrict__ b1,
    const float* __restrict__ W2, const float* __restrict__ b2,
    const float* __restrict__ W3, const float* __restrict__ b3,
    const float* __restrict__ W4, const float* __restrict__ b4,
    float* __restrict__ dout, int n)
{
    __shared__ float lw[2368];
    const int tid = threadIdx.x;
    for (int idx = tid; idx < 2368; idx += 256) {
        float v = 0.f;
        if (idx < 288)        { int tt = idx,        r = tt >> 5, c = tt & 31; v = (c < DH) ? W1[r * DH + c] : 0.f; }
        else if (idx < 1248)  { int tt = idx - 288,  r = tt >> 5, c = tt & 31; v = (c < DH) ? W2[r * DH + c] : 0.f; }
        else if (idx < 2208)  { int tt = idx - 1248, r = tt >> 5, c = tt & 31; v = (c < DH) ? W3[r * DH + c] : 0.f; }
        else if (idx < 2240)  { int c = idx - 2208; v = (c < DH) ? b1[c] : 0.f; }
        else if (idx < 2272)  { int c = idx - 2240; v = (c < DH) ? b2[c] : 0.f; }
        else if (idx < 2304)  { int c = idx - 2272; v = (c < DH) ? b3[c] : 0.f; }
        else if (idx < 2336)  { int c = idx - 2304; v = (c < DH) ? W4[c] : 0.f; }
        else if (idx == 2336) { v = b4[0]; }
        lw[idx] = v;
    }
    __syncthreads();

    const int i = blockIdx.x * 256 + tid;
    if (i >= n) return;

    const float4 vpe = pe[i];
    const float4 vs  = s[i];
    const float  vq  = q[i];
    float x[9] = { vpe.x, vpe.y, vpe.z, vpe.w, vq, vs.x, vs.y, vs.z, vs.w };

    v2 acc[15];
    v2 hh[15];
    unsigned m1 = 0, m2 = 0, m3 = 0;
    const v2 slope2 = { SLOPE, SLOPE };

    // row-wide fma: 7x float4 + 1x v2 LDS reads; per-jj fma order identical
    // to R13 (jj ascending, same component pairing) -> forward bit-identical.
    #define ROW_FMA(OFF, k, sv)                                               \
    {                                                                         \
        const float4* Wr4 = reinterpret_cast<const float4*>(lw + OFF + (k)*32);\
        const v2*     Wr2 = reinterpret_cast<const v2*>(lw + OFF + (k)*32);   \
        _Pragma("unroll")                                                     \
        for (int j4 = 0; j4 < 7; ++j4) {                                      \
            const float4 w = Wr4[j4];                                         \
            const v2 wlo = { w.x, w.y };                                      \
            const v2 whi = { w.z, w.w };                                      \
            acc[2*j4]   = __builtin_elementwise_fma(sv, wlo, acc[2*j4]);      \
            acc[2*j4+1] = __builtin_elementwise_fma(sv, whi, acc[2*j4+1]);    \
        }                                                                     \
        acc[14] = __builtin_elementwise_fma(sv, Wr2[14], acc[14]);            \
    }

    // ---- layer 1: (x @ W1) then + b1 (acc from 0, k ascending, fma) ----
    #pragma unroll
    for (int jj = 0; jj < 15; ++jj) acc[jj] = (v2){0.f, 0.f};
    #pragma unroll
    for (int k = 0; k < 9; ++k) {
        const v2 xv = { x[k], x[k] };
        ROW_FMA(W1_OFF, k, xv);
    }
    {
        const v2* bv = reinterpret_cast<const v2*>(lw + B1_OFF);
        #pragma unroll
        for (int jj = 0; jj < 15; ++jj) {
            const v2 z = acc[jj] + bv[jj];
            if (z.x > 0.f) m1 |= (1u << (2*jj));
            if (z.y > 0.f) m1 |= (1u << (2*jj+1));
            hh[jj] = __builtin_elementwise_max(z, z * slope2);  // bit-identical LeakyReLU
        }
    }

    // ---- layer 2 ----
    #pragma unroll
    for (int jj = 0; jj < 15; ++jj) acc[jj] = (v2){0.f, 0.f};
    #pragma unroll
    for (int k = 0; k < DH; ++k) {
        const float hk = hh[k >> 1][k & 1];
        const v2 hv = { hk, hk };
        ROW_FMA(W2_OFF, k, hv);
    }
    {
        const v2* bv = reinterpret_cast<const v2*>(lw + B2_OFF);
        #pragma unroll
        for (int jj = 0; jj < 15; ++jj) {
            const v2 z = acc[jj] + bv[jj];
            if (z.x > 0.f) m2 |= (1u << (2*jj));
            if (z.y > 0.f) m2 |= (1u << (2*jj+1));
            hh[jj] = __builtin_elementwise_max(z, z * slope2);
        }
    }

    // ---- layer 3 ----
    #pragma unroll
    for (int jj = 0; jj < 15; ++jj) acc[jj] = (v2){0.f, 0.f};
    #pragma unroll
    for (int k = 0; k < DH; ++k) {
        const float hk = hh[k >> 1][k & 1];
        const v2 hv = { hk, hk };
        ROW_FMA(W3_OFF, k, hv);
    }
    // output dot: scalar, j ascending (bit-identical to R13)
    const float* b3p = lw + B3_OFF;
    const float* W4p = lw + W4_OFF;
    float outv = 0.f;
    #pragma unroll
    for (int j = 0; j < DH; ++j) {
        const float z = acc[j >> 1][j & 1] + b3p[j];
        if (z > 0.f) m3 |= (1u << j);
        const float hz = (z > 0.f) ? z : SLOPE * z;
        outv = fmaf(hz, W4p[j], outv);
    }
    outv += lw[B4_OFF];

    // ---- backward (mask-driven; value-continuous) ----
    v2 g3[15];
    {
        const v2* w4v = reinterpret_cast<const v2*>(W4p);
        #pragma unroll
        for (int jj = 0; jj < 15; ++jj) {
            const v2 w = w4v[jj];
            g3[jj].x = ((m3 >> (2*jj))   & 1u) ? w.x : SLOPE * w.x;
            g3[jj].y = ((m3 >> (2*jj+1)) & 1u) ? w.y : SLOPE * w.y;
        }
    }
    #define ROW_DOT(OFF, k, G, D)                                             \
    {                                                                         \
        const float4* Wr4 = reinterpret_cast<const float4*>(lw + OFF + (k)*32);\
        const v2*     Wr2 = reinterpret_cast<const v2*>(lw + OFF + (k)*32);   \
        v2 da = (v2){0.f, 0.f}, db = (v2){0.f, 0.f};                          \
        _Pragma("unroll")                                                     \
        for (int j4 = 0; j4 < 7; ++j4) {                                      \
            const float4 w = Wr4[j4];                                         \
            const v2 wlo = { w.x, w.y };                                      \
            const v2 whi = { w.z, w.w };                                      \
            da = __builtin_elementwise_fma(G[2*j4],   wlo, da);               \
            db = __builtin_elementwise_fma(G[2*j4+1], whi, db);               \
        }                                                                     \
        da = __builtin_elementwise_fma(G[14], Wr2[14], da);                   \
        D = (da.x + da.y) + (db.x + db.y);                                    \
    }

    v2 g2[15];
    #pragma unroll
    for (int k = 0; k < DH; ++k) {
        float dot;
        ROW_DOT(W3_OFF, k, g3, dot);
        g2[k >> 1][k & 1] = ((m2 >> k) & 1u) ? dot : SLOPE * dot;
    }
    v2 g1[15];
    #pragma unroll
    for (int k = 0; k < DH; ++k) {
        float dot;
        ROW_DOT(W2_OFF, k, g2, dot);
        g1[k >> 1][k & 1] = ((m1 >> k) & 1u) ? dot : SLOPE * dot;
    }
    float gx[9];
    #pragma unroll
    for (int k = 0; k < 9; ++k) {
        float dot;
        ROW_DOT(W1_OFF, k, g1, dot);
        gx[k] = dot;
    }

    // ---- stores: [out(N) | h_s(4N) | h_q(N) | h_pe(4N)] ----
    dout[i] = outv;
    float4* hs = reinterpret_cast<float4*>(dout + (size_t)n);
    hs[i] = make_float4(gx[5], gx[6], gx[7], gx[8]);
    dout[(size_t)5 * n + i] = gx[4];
    float4* hpe = reinterpret_cast<float4*>(dout + (size_t)6 * n);
    hpe[i] = make_float4(gx[0], gx[1], gx[2], gx[3]);
}

extern "C" void kernel_launch(void* const* d_in, const int* in_sizes, int n_in,
                              void* d_out, int out_size, void* d_ws, size_t ws_size,
                              hipStream_t stream) {
    const int n = in_sizes[1];  // input_q has N elements
    const int blocks = (n + 255) / 256;
    hipLaunchKernelGGL(mlp_fwdbwd, dim3(blocks), dim3(256), 0, stream,
        (const float4*)d_in[0], (const float*)d_in[1], (const float4*)d_in[2],
        (const float*)d_in[3], (const float*)d_in[4],
        (const float*)d_in[5], (const float*)d_in[6],
        (const float*)d_in[7], (const float*)d_in[8],
        (const float*)d_in[9], (const float*)d_in[10],
        (float*)d_out, n);
}

// Round 16
// 4175.513 us; speedup vs baseline: 1.6625x; 1.4121x over previous
//
#include <hip/hip_runtime.h>

#define DH 30
#define SLOPE 0.01f

typedef float v2 __attribute__((ext_vector_type(2)));

// LDS layout (floats): W1[9][32]@0, W2[30][32]@288, W3[30][32]@1248,
// b1[32]@2208, b2[32]@2240, b3[32]@2272, W4[32]@2304, b4@2336. Pads zero.
#define W1_OFF 0
#define W2_OFF 288
#define W3_OFF 1248
#define B1_OFF 2208
#define B2_OFF 2240
#define B3_OFF 2272
#define W4_OFF 2304
#define B4_OFF 2336

// R15 with the correct cap. Empirical VGPR-cap law: cap ~ 256/min_waves
// ((256,4)->64, (256,6)->40, (256,7)->36). Live set ~78 -> min_waves=3
// (cap ~85) is the only non-spilling choice; 6 squeezed to 40 -> 21.7GB
// spills (R15). No in-loop sched_barriers: LDS counted lgkmcnt + pressure-
// aware scheduling under the 85-cap should pipeline ds_reads across rows.
// float4 row reads: 8 ds-ops/row vs R13's 15. 1 sample/thread (R7/R14).
__global__ __launch_bounds__(256, 3) void mlp_fwdbwd(
    const float4* __restrict__ pe,
    const float*  __restrict__ q,
    const float4* __restrict__ s,
    const float* __restrict__ W1, const float* __restrict__ b1,
    const float* __restrict__ W2, const float* __restrict__ b2,
    const float* __restrict__ W3, const float* __restrict__ b3,
    const float* __restrict__ W4, const float* __restrict__ b4,
    float* __restrict__ dout, int n)
{
    __shared__ float lw[2368];
    const int tid = threadIdx.x;
    for (int idx = tid; idx < 2368; idx += 256) {
        float v = 0.f;
        if (idx < 288)        { int tt = idx,        r = tt >> 5, c = tt & 31; v = (c < DH) ? W1[r * DH + c] : 0.f; }
        else if (idx < 1248)  { int tt = idx - 288,  r = tt >> 5, c = tt & 31; v = (c < DH) ? W2[r * DH + c] : 0.f; }
        else if (idx < 2208)  { int tt = idx - 1248, r = tt >> 5, c = tt & 31; v = (c < DH) ? W3[r * DH + c] : 0.f; }
        else if (idx < 2240)  { int c = idx - 2208; v = (c < DH) ? b1[c] : 0.f; }
        else if (idx < 2272)  { int c = idx - 2240; v = (c < DH) ? b2[c] : 0.f; }
        else if (idx < 2304)  { int c = idx - 2272; v = (c < DH) ? b3[c] : 0.f; }
        else if (idx < 2336)  { int c = idx - 2304; v = (c < DH) ? W4[c] : 0.f; }
        else if (idx == 2336) { v = b4[0]; }
        lw[idx] = v;
    }
    __syncthreads();

    const int i = blockIdx.x * 256 + tid;
    if (i >= n) return;

    const float4 vpe = pe[i];
    const float4 vs  = s[i];
    const float  vq  = q[i];
    float x[9] = { vpe.x, vpe.y, vpe.z, vpe.w, vq, vs.x, vs.y, vs.z, vs.w };

    v2 acc[15];
    v2 hh[15];
    unsigned m1 = 0, m2 = 0, m3 = 0;
    const v2 slope2 = { SLOPE, SLOPE };

    // row-wide fma: 7x float4 + 1x v2 LDS reads; per-jj fma order identical
    // to R13 (jj ascending, same component pairing) -> forward bit-identical.
    #define ROW_FMA(OFF, k, sv)                                               \
    {                                                                         \
        const float4* Wr4 = reinterpret_cast<const float4*>(lw + OFF + (k)*32);\
        const v2*     Wr2 = reinterpret_cast<const v2*>(lw + OFF + (k)*32);   \
        _Pragma("unroll")                                                     \
        for (int j4 = 0; j4 < 7; ++j4) {                                      \
            const float4 w = Wr4[j4];                                         \
            const v2 wlo = { w.x, w.y };                                      \
            const v2 whi = { w.z, w.w };                                      \
            acc[2*j4]   = __builtin_elementwise_fma(sv, wlo, acc[2*j4]);      \
            acc[2*j4+1] = __builtin_elementwise_fma(sv, whi, acc[2*j4+1]);    \
        }                                                                     \
        acc[14] = __builtin_elementwise_fma(sv, Wr2[14], acc[14]);            \
    }

    // ---- layer 1: (x @ W1) then + b1 (acc from 0, k ascending, fma) ----
    #pragma unroll
    for (int jj = 0; jj < 15; ++jj) acc[jj] = (v2){0.f, 0.f};
    #pragma unroll
    for (int k = 0; k < 9; ++k) {
        const v2 xv = { x[k], x[k] };
        ROW_FMA(W1_OFF, k, xv);
    }
    {
        const v2* bv = reinterpret_cast<const v2*>(lw + B1_OFF);
        #pragma unroll
        for (int jj = 0; jj < 15; ++jj) {
            const v2 z = acc[jj] + bv[jj];
            if (z.x > 0.f) m1 |= (1u << (2*jj));
            if (z.y > 0.f) m1 |= (1u << (2*jj+1));
            hh[jj] = __builtin_elementwise_max(z, z * slope2);  // bit-identical LeakyReLU
        }
    }

    // ---- layer 2 ----
    #pragma unroll
    for (int jj = 0; jj < 15; ++jj) acc[jj] = (v2){0.f, 0.f};
    #pragma unroll
    for (int k = 0; k < DH; ++k) {
        const float hk = hh[k >> 1][k & 1];
        const v2 hv = { hk, hk };
        ROW_FMA(W2_OFF, k, hv);
    }
    {
        const v2* bv = reinterpret_cast<const v2*>(lw + B2_OFF);
        #pragma unroll
        for (int jj = 0; jj < 15; ++jj) {
            const v2 z = acc[jj] + bv[jj];
            if (z.x > 0.f) m2 |= (1u << (2*jj));
            if (z.y > 0.f) m2 |= (1u << (2*jj+1));
            hh[jj] = __builtin_elementwise_max(z, z * slope2);
        }
    }

    // ---- layer 3 ----
    #pragma unroll
    for (int jj = 0; jj < 15; ++jj) acc[jj] = (v2){0.f, 0.f};
    #pragma unroll
    for (int k = 0; k < DH; ++k) {
        const float hk = hh[k >> 1][k & 1];
        const v2 hv = { hk, hk };
        ROW_FMA(W3_OFF, k, hv);
    }
    // output dot: scalar, j ascending (bit-identical to R13)
    const float* b3p = lw + B3_OFF;
    const float* W4p = lw + W4_OFF;
    float outv = 0.f;
    #pragma unroll
    for (int j = 0; j < DH; ++j) {
        const float z = acc[j >> 1][j & 1] + b3p[j];
        if (z > 0.f) m3 |= (1u << j);
        const float hz = (z > 0.f) ? z : SLOPE * z;
        outv = fmaf(hz, W4p[j], outv);
    }
    outv += lw[B4_OFF];

    // ---- backward (mask-driven; value-continuous) ----
    v2 g3[15];
    {
        const v2* w4v = reinterpret_cast<const v2*>(W4p);
        #pragma unroll
        for (int jj = 0; jj < 15; ++jj) {
            const v2 w = w4v[jj];
            g3[jj].x = ((m3 >> (2*jj))   & 1u) ? w.x : SLOPE * w.x;
            g3[jj].y = ((m3 >> (2*jj+1)) & 1u) ? w.y : SLOPE * w.y;
        }
    }
    #define ROW_DOT(OFF, k, G, D)                                             \
    {                                                                         \
        const float4* Wr4 = reinterpret_cast<const float4*>(lw + OFF + (k)*32);\
        const v2*     Wr2 = reinterpret_cast<const v2*>(lw + OFF + (k)*32);   \
        v2 da = (v2){0.f, 0.f}, db = (v2){0.f, 0.f};                          \
        _Pragma("unroll")                                                     \
        for (int j4 = 0; j4 < 7; ++j4) {                                      \
            const float4 w = Wr4[j4];                                         \
            const v2 wlo = { w.x, w.y };                                      \
            const v2 whi = { w.z, w.w };                                      \
            da = __builtin_elementwise_fma(G[2*j4],   wlo, da);               \
            db = __builtin_elementwise_fma(G[2*j4+1], whi, db);               \
        }                                                                     \
        da = __builtin_elementwise_fma(G[14], Wr2[14], da);                   \
        D = (da.x + da.y) + (db.x + db.y);                                    \
    }

    v2 g2[15];
    #pragma unroll
    for (int k = 0; k < DH; ++k) {
        float dot;
        ROW_DOT(W3_OFF, k, g3, dot);
        g2[k >> 1][k & 1] = ((m2 >> k) & 1u) ? dot : SLOPE * dot;
    }
    v2 g1[15];
    #pragma unroll
    for (int k = 0; k < DH; ++k) {
        float dot;
        ROW_DOT(W2_OFF, k, g2, dot);
        g1[k >> 1][k & 1] = ((m1 >> k) & 1u) ? dot : SLOPE * dot;
    }
    float gx[9];
    #pragma unroll
    for (int k = 0; k < 9; ++k) {
        float dot;
        ROW_DOT(W1_OFF, k, g1, dot);
        gx[k] = dot;
    }

    // ---- stores: [out(N) | h_s(4N) | h_q(N) | h_pe(4N)] ----
    dout[i] = outv;
    float4* hs = reinterpret_cast<float4*>(dout + (size_t)n);
    hs[i] = make_float4(gx[5], gx[6], gx[7], gx[8]);
    dout[(size_t)5 * n + i] = gx[4];
    float4* hpe = reinterpret_cast<float4*>(dout + (size_t)6 * n);
    hpe[i] = make_float4(gx[0], gx[1], gx[2], gx[3]);
}

extern "C" void kernel_launch(void* const* d_in, const int* in_sizes, int n_in,
                              void* d_out, int out_size, void* d_ws, size_t ws_size,
                              hipStream_t stream) {
    const int n = in_sizes[1];  // input_q has N elements
    const int blocks = (n + 255) / 256;
    hipLaunchKernelGGL(mlp_fwdbwd, dim3(blocks), dim3(256), 0, stream,
        (const float4*)d_in[0], (const float*)d_in[1], (const float4*)d_in[2],
        (const float*)d_in[3], (const float*)d_in[4],
        (const float*)d_in[5], (const float*)d_in[6],
        (const float*)d_in[7], (const float*)d_in[8],
        (const float*)d_in[9], (const float*)d_in[10],
        (float*)d_out, n);
}

// Round 17
// 153.784 us; speedup vs baseline: 45.1401x; 27.1517x over previous
//
#include <hip/hip_runtime.h>

#define DH 30
#define SLOPE 0.01f

typedef float v2 __attribute__((ext_vector_type(2)));
#define SB() __builtin_amdgcn_sched_barrier(0)

// LDS layout (floats): W1[9][32]@0, W2[30][32]@288, W3[30][32]@1248,
// b1[32]@2208, b2[32]@2240, b3[32]@2272, W4[32]@2304, b4@2336. Pads zero.
#define W1_OFF 0
#define W2_OFF 288
#define W3_OFF 1248
#define B1_OFF 2208
#define B2_OFF 2240
#define B3_OFF 2272
#define W4_OFF 2304
#define B4_OFF 2336

// R13 (152us champion: LDS weights + per-row SB fences + (256,3) cap) with
// ONE delta: float4 row reads (7x b128 + 1x b64 = 8 ds-ops/row vs 15).
// R16 proved fences are load-bearing: without SB() the pre-RA scheduler
// hoists the whole ds_read stream and RA spills at ANY cap (VGPR 84 but
// 14.4GB scratch traffic). R13 model: LDS-pipe-throughput bound -> halving
// ds-ops/row should cut the bound ~2x. 1 sample/thread (R7/R14: 2-sample
// never fits registers).
__global__ __launch_bounds__(256, 3) void mlp_fwdbwd(
    const float4* __restrict__ pe,
    const float*  __restrict__ q,
    const float4* __restrict__ s,
    const float* __restrict__ W1, const float* __restrict__ b1,
    const float* __restrict__ W2, const float* __restrict__ b2,
    const float* __restrict__ W3, const float* __restrict__ b3,
    const float* __restrict__ W4, const float* __restrict__ b4,
    float* __restrict__ dout, int n)
{
    __shared__ float lw[2368];
    const int tid = threadIdx.x;
    for (int idx = tid; idx < 2368; idx += 256) {
        float v = 0.f;
        if (idx < 288)        { int tt = idx,        r = tt >> 5, c = tt & 31; v = (c < DH) ? W1[r * DH + c] : 0.f; }
        else if (idx < 1248)  { int tt = idx - 288,  r = tt >> 5, c = tt & 31; v = (c < DH) ? W2[r * DH + c] : 0.f; }
        else if (idx < 2208)  { int tt = idx - 1248, r = tt >> 5, c = tt & 31; v = (c < DH) ? W3[r * DH + c] : 0.f; }
        else if (idx < 2240)  { int c = idx - 2208; v = (c < DH) ? b1[c] : 0.f; }
        else if (idx < 2272)  { int c = idx - 2240; v = (c < DH) ? b2[c] : 0.f; }
        else if (idx < 2304)  { int c = idx - 2272; v = (c < DH) ? b3[c] : 0.f; }
        else if (idx < 2336)  { int c = idx - 2304; v = (c < DH) ? W4[c] : 0.f; }
        else if (idx == 2336) { v = b4[0]; }
        lw[idx] = v;
    }
    __syncthreads();

    const int i = blockIdx.x * 256 + tid;
    if (i >= n) return;

    const float4 vpe = pe[i];
    const float4 vs  = s[i];
    const float  vq  = q[i];
    float x[9] = { vpe.x, vpe.y, vpe.z, vpe.w, vq, vs.x, vs.y, vs.z, vs.w };

    v2 acc[15];
    v2 hh[15];
    unsigned m1 = 0, m2 = 0, m3 = 0;
    const v2 slope2 = { SLOPE, SLOPE };

    // row-wide fma: 7x float4 + 1x v2 LDS reads; per-jj fma order identical
    // to R13 (jj ascending, same component pairing) -> forward bit-identical.
    // SB() after each row bounds the scheduler's live set (R16 lesson).
    #define ROW_FMA(OFF, k, sv)                                               \
    {                                                                         \
        const float4* Wr4 = reinterpret_cast<const float4*>(lw + OFF + (k)*32);\
        const v2*     Wr2 = reinterpret_cast<const v2*>(lw + OFF + (k)*32);   \
        _Pragma("unroll")                                                     \
        for (int j4 = 0; j4 < 7; ++j4) {                                      \
            const float4 w = Wr4[j4];                                         \
            const v2 wlo = { w.x, w.y };                                      \
            const v2 whi = { w.z, w.w };                                      \
            acc[2*j4]   = __builtin_elementwise_fma(sv, wlo, acc[2*j4]);      \
            acc[2*j4+1] = __builtin_elementwise_fma(sv, whi, acc[2*j4+1]);    \
        }                                                                     \
        acc[14] = __builtin_elementwise_fma(sv, Wr2[14], acc[14]);            \
    }

    // ---- layer 1: (x @ W1) then + b1 (acc from 0, k ascending, fma) ----
    #pragma unroll
    for (int jj = 0; jj < 15; ++jj) acc[jj] = (v2){0.f, 0.f};
    #pragma unroll
    for (int k = 0; k < 9; ++k) {
        const v2 xv = { x[k], x[k] };
        ROW_FMA(W1_OFF, k, xv);
        SB();
    }
    {
        const v2* bv = reinterpret_cast<const v2*>(lw + B1_OFF);
        #pragma unroll
        for (int jj = 0; jj < 15; ++jj) {
            const v2 z = acc[jj] + bv[jj];
            if (z.x > 0.f) m1 |= (1u << (2*jj));
            if (z.y > 0.f) m1 |= (1u << (2*jj+1));
            hh[jj] = __builtin_elementwise_max(z, z * slope2);  // bit-identical LeakyReLU
        }
    }
    SB();

    // ---- layer 2 ----
    #pragma unroll
    for (int jj = 0; jj < 15; ++jj) acc[jj] = (v2){0.f, 0.f};
    #pragma unroll
    for (int k = 0; k < DH; ++k) {
        const float hk = hh[k >> 1][k & 1];
        const v2 hv = { hk, hk };
        ROW_FMA(W2_OFF, k, hv);
        SB();
    }
    {
        const v2* bv = reinterpret_cast<const v2*>(lw + B2_OFF);
        #pragma unroll
        for (int jj = 0; jj < 15; ++jj) {
            const v2 z = acc[jj] + bv[jj];
            if (z.x > 0.f) m2 |= (1u << (2*jj));
            if (z.y > 0.f) m2 |= (1u << (2*jj+1));
            hh[jj] = __builtin_elementwise_max(z, z * slope2);
        }
    }
    SB();

    // ---- layer 3 ----
    #pragma unroll
    for (int jj = 0; jj < 15; ++jj) acc[jj] = (v2){0.f, 0.f};
    #pragma unroll
    for (int k = 0; k < DH; ++k) {
        const float hk = hh[k >> 1][k & 1];
        const v2 hv = { hk, hk };
        ROW_FMA(W3_OFF, k, hv);
        SB();
    }
    // output dot: scalar, j ascending (bit-identical to R13)
    const float* b3p = lw + B3_OFF;
    const float* W4p = lw + W4_OFF;
    float outv = 0.f;
    #pragma unroll
    for (int j = 0; j < DH; ++j) {
        const float z = acc[j >> 1][j & 1] + b3p[j];
        if (z > 0.f) m3 |= (1u << j);
        const float hz = (z > 0.f) ? z : SLOPE * z;
        outv = fmaf(hz, W4p[j], outv);
    }
    outv += lw[B4_OFF];
    SB();

    // ---- backward (mask-driven; value-continuous) ----
    v2 g3[15];
    {
        const v2* w4v = reinterpret_cast<const v2*>(W4p);
        #pragma unroll
        for (int jj = 0; jj < 15; ++jj) {
            const v2 w = w4v[jj];
            g3[jj].x = ((m3 >> (2*jj))   & 1u) ? w.x : SLOPE * w.x;
            g3[jj].y = ((m3 >> (2*jj+1)) & 1u) ? w.y : SLOPE * w.y;
        }
    }
    #define ROW_DOT(OFF, k, G, D)                                             \
    {                                                                         \
        const float4* Wr4 = reinterpret_cast<const float4*>(lw + OFF + (k)*32);\
        const v2*     Wr2 = reinterpret_cast<const v2*>(lw + OFF + (k)*32);   \
        v2 da = (v2){0.f, 0.f}, db = (v2){0.f, 0.f};                          \
        _Pragma("unroll")                                                     \
        for (int j4 = 0; j4 < 7; ++j4) {                                      \
            const float4 w = Wr4[j4];                                         \
            const v2 wlo = { w.x, w.y };                                      \
            const v2 whi = { w.z, w.w };                                      \
            da = __builtin_elementwise_fma(G[2*j4],   wlo, da);               \
            db = __builtin_elementwise_fma(G[2*j4+1], whi, db);               \
        }                                                                     \
        da = __builtin_elementwise_fma(G[14], Wr2[14], da);                   \
        D = (da.x + da.y) + (db.x + db.y);                                    \
    }

    v2 g2[15];
    #pragma unroll
    for (int k = 0; k < DH; ++k) {
        float dot;
        ROW_DOT(W3_OFF, k, g3, dot);
        g2[k >> 1][k & 1] = ((m2 >> k) & 1u) ? dot : SLOPE * dot;
        SB();
    }
    v2 g1[15];
    #pragma unroll
    for (int k = 0; k < DH; ++k) {
        float dot;
        ROW_DOT(W2_OFF, k, g2, dot);
        g1[k >> 1][k & 1] = ((m1 >> k) & 1u) ? dot : SLOPE * dot;
        SB();
    }
    float gx[9];
    #pragma unroll
    for (int k = 0; k < 9; ++k) {
        float dot;
        ROW_DOT(W1_OFF, k, g1, dot);
        gx[k] = dot;
        SB();
    }

    // ---- stores: [out(N) | h_s(4N) | h_q(N) | h_pe(4N)] ----
    dout[i] = outv;
    float4* hs = reinterpret_cast<float4*>(dout + (size_t)n);
    hs[i] = make_float4(gx[5], gx[6], gx[7], gx[8]);
    dout[(size_t)5 * n + i] = gx[4];
    float4* hpe = reinterpret_cast<float4*>(dout + (size_t)6 * n);
    hpe[i] = make_float4(gx[0], gx[1], gx[2], gx[3]);
}

extern "C" void kernel_launch(void* const* d_in, const int* in_sizes, int n_in,
                              void* d_out, int out_size, void* d_ws, size_t ws_size,
                              hipStream_t stream) {
    const int n = in_sizes[1];  // input_q has N elements
    const int blocks = (n + 255) / 256;
    hipLaunchKernelGGL(mlp_fwdbwd, dim3(blocks), dim3(256), 0, stream,
        (const float4*)d_in[0], (const float*)d_in[1], (const float4*)d_in[2],
        (const float*)d_in[3], (const float*)d_in[4],
        (const float*)d_in[5], (const float*)d_in[6],
        (const float*)d_in[7], (const float*)d_in[8],
        (const float*)d_in[9], (const float*)d_in[10],
        (float*)d_out, n);
}

// Round 18
// 134.161 us; speedup vs baseline: 51.7426x; 1.1463x over previous
//
#include <hip/hip_runtime.h>

#define DH 30
#define SLOPE 0.01f

typedef float v2 __attribute__((ext_vector_type(2)));
#define SB() __builtin_amdgcn_sched_barrier(0)

// LDS layout (floats): W1[9][32]@0, W2[30][32]@288, W3[30][32]@1248,
// b1[32]@2208, b2[32]@2240, b3[32]@2272, W4[32]@2304, b4@2336. Pads zero.
#define W1_OFF 0
#define W2_OFF 288
#define W3_OFF 1248
#define B1_OFF 2208
#define B2_OFF 2240
#define B3_OFF 2272
#define W4_OFF 2304
#define B4_OFF 2336

// Pipe-split kernel. R13=R17 (ops differ 2x, bytes equal, same time) proved
// the LDS port replicates broadcast bytes -> we sit at ~88% of the LDS-port
// roofline streaming all 4200 weight-dwords/sample through LDS. Split:
// FORWARD via LDS (R17 verbatim: fenced rows, float4 reads), BACKWARD via
// the scalar SMEM pipe (R8 verbatim: s_load->SGPR operand; SGPR budget
// self-caps hoisting, no fences needed, no VGPR weight cost). Waves at
// different phases use different pipes -> per-pipe bytes halve.
__global__ __launch_bounds__(256, 3) void mlp_fwdbwd(
    const float4* __restrict__ pe,
    const float*  __restrict__ q,
    const float4* __restrict__ s,
    const float* __restrict__ W1, const float* __restrict__ b1,
    const float* __restrict__ W2, const float* __restrict__ b2,
    const float* __restrict__ W3, const float* __restrict__ b3,
    const float* __restrict__ W4, const float* __restrict__ b4,
    float* __restrict__ dout, int n)
{
    __shared__ float lw[2368];
    const int tid = threadIdx.x;
    for (int idx = tid; idx < 2368; idx += 256) {
        float v = 0.f;
        if (idx < 288)        { int tt = idx,        r = tt >> 5, c = tt & 31; v = (c < DH) ? W1[r * DH + c] : 0.f; }
        else if (idx < 1248)  { int tt = idx - 288,  r = tt >> 5, c = tt & 31; v = (c < DH) ? W2[r * DH + c] : 0.f; }
        else if (idx < 2208)  { int tt = idx - 1248, r = tt >> 5, c = tt & 31; v = (c < DH) ? W3[r * DH + c] : 0.f; }
        else if (idx < 2240)  { int c = idx - 2208; v = (c < DH) ? b1[c] : 0.f; }
        else if (idx < 2272)  { int c = idx - 2240; v = (c < DH) ? b2[c] : 0.f; }
        else if (idx < 2304)  { int c = idx - 2272; v = (c < DH) ? b3[c] : 0.f; }
        else if (idx < 2336)  { int c = idx - 2304; v = (c < DH) ? W4[c] : 0.f; }
        else if (idx == 2336) { v = b4[0]; }
        lw[idx] = v;
    }
    __syncthreads();

    const int i = blockIdx.x * 256 + tid;
    if (i >= n) return;

    const float4 vpe = pe[i];
    const float4 vs  = s[i];
    const float  vq  = q[i];
    float x[9] = { vpe.x, vpe.y, vpe.z, vpe.w, vq, vs.x, vs.y, vs.z, vs.w };

    v2 acc[15];
    v2 hh[15];
    unsigned m1 = 0, m2 = 0, m3 = 0;
    const v2 slope2 = { SLOPE, SLOPE };

    // row-wide fma: 7x float4 + 1x v2 LDS reads; per-jj fma order identical
    // to R13/R17 -> forward bit-identical. SB() per row (R16: load-bearing).
    #define ROW_FMA(OFF, k, sv)                                               \
    {                                                                         \
        const float4* Wr4 = reinterpret_cast<const float4*>(lw + OFF + (k)*32);\
        const v2*     Wr2 = reinterpret_cast<const v2*>(lw + OFF + (k)*32);   \
        _Pragma("unroll")                                                     \
        for (int j4 = 0; j4 < 7; ++j4) {                                      \
            const float4 w = Wr4[j4];                                         \
            const v2 wlo = { w.x, w.y };                                      \
            const v2 whi = { w.z, w.w };                                      \
            acc[2*j4]   = __builtin_elementwise_fma(sv, wlo, acc[2*j4]);      \
            acc[2*j4+1] = __builtin_elementwise_fma(sv, whi, acc[2*j4+1]);    \
        }                                                                     \
        acc[14] = __builtin_elementwise_fma(sv, Wr2[14], acc[14]);            \
    }

    // ---- layer 1: (x @ W1) then + b1 (acc from 0, k ascending, fma) ----
    #pragma unroll
    for (int jj = 0; jj < 15; ++jj) acc[jj] = (v2){0.f, 0.f};
    #pragma unroll
    for (int k = 0; k < 9; ++k) {
        const v2 xv = { x[k], x[k] };
        ROW_FMA(W1_OFF, k, xv);
        SB();
    }
    {
        const v2* bv = reinterpret_cast<const v2*>(lw + B1_OFF);
        #pragma unroll
        for (int jj = 0; jj < 15; ++jj) {
            const v2 z = acc[jj] + bv[jj];
            if (z.x > 0.f) m1 |= (1u << (2*jj));
            if (z.y > 0.f) m1 |= (1u << (2*jj+1));
            hh[jj] = __builtin_elementwise_max(z, z * slope2);  // bit-identical LeakyReLU
        }
    }
    SB();

    // ---- layer 2 ----
    #pragma unroll
    for (int jj = 0; jj < 15; ++jj) acc[jj] = (v2){0.f, 0.f};
    #pragma unroll
    for (int k = 0; k < DH; ++k) {
        const float hk = hh[k >> 1][k & 1];
        const v2 hv = { hk, hk };
        ROW_FMA(W2_OFF, k, hv);
        SB();
    }
    {
        const v2* bv = reinterpret_cast<const v2*>(lw + B2_OFF);
        #pragma unroll
        for (int jj = 0; jj < 15; ++jj) {
            const v2 z = acc[jj] + bv[jj];
            if (z.x > 0.f) m2 |= (1u << (2*jj));
            if (z.y > 0.f) m2 |= (1u << (2*jj+1));
            hh[jj] = __builtin_elementwise_max(z, z * slope2);
        }
    }
    SB();

    // ---- layer 3 ----
    #pragma unroll
    for (int jj = 0; jj < 15; ++jj) acc[jj] = (v2){0.f, 0.f};
    #pragma unroll
    for (int k = 0; k < DH; ++k) {
        const float hk = hh[k >> 1][k & 1];
        const v2 hv = { hk, hk };
        ROW_FMA(W3_OFF, k, hv);
        SB();
    }
    // output dot: scalar, j ascending (bit-identical to R13/R17)
    const float* b3p = lw + B3_OFF;
    const float* W4p = lw + W4_OFF;
    float outv = 0.f;
    #pragma unroll
    for (int j = 0; j < DH; ++j) {
        const float z = acc[j >> 1][j & 1] + b3p[j];
        if (z > 0.f) m3 |= (1u << j);
        const float hz = (z > 0.f) ? z : SLOPE * z;
        outv = fmaf(hz, W4p[j], outv);
    }
    outv += lw[B4_OFF];
    SB();

    // ---- backward: R8's SMEM path verbatim (global W*, s_load -> SGPR
    // operand; value-continuous, mask-driven). No LDS traffic here. ----
    v2 g3[15];
    {
        #pragma unroll
        for (int jj = 0; jj < 15; ++jj) {
            const float wx = W4[2*jj];
            const float wy = W4[2*jj+1];
            g3[jj].x = ((m3 >> (2*jj))   & 1u) ? wx : SLOPE * wx;
            g3[jj].y = ((m3 >> (2*jj+1)) & 1u) ? wy : SLOPE * wy;
        }
    }
    v2 g2[15];
    #pragma unroll
    for (int k = 0; k < DH; ++k) {
        v2 d = (v2){0.f, 0.f};
        const v2* Wr = reinterpret_cast<const v2*>(W3 + k * DH);
        #pragma unroll
        for (int jj = 0; jj < 15; ++jj)
            d = __builtin_elementwise_fma(g3[jj], Wr[jj], d);
        const float dot = d.x + d.y;
        g2[k >> 1][k & 1] = ((m2 >> k) & 1u) ? dot : SLOPE * dot;
    }
    v2 g1[15];
    #pragma unroll
    for (int k = 0; k < DH; ++k) {
        v2 d = (v2){0.f, 0.f};
        const v2* Wr = reinterpret_cast<const v2*>(W2 + k * DH);
        #pragma unroll
        for (int jj = 0; jj < 15; ++jj)
            d = __builtin_elementwise_fma(g2[jj], Wr[jj], d);
        const float dot = d.x + d.y;
        g1[k >> 1][k & 1] = ((m1 >> k) & 1u) ? dot : SLOPE * dot;
    }
    float gx[9];
    #pragma unroll
    for (int k = 0; k < 9; ++k) {
        v2 d = (v2){0.f, 0.f};
        const v2* Wr = reinterpret_cast<const v2*>(W1 + k * DH);
        #pragma unroll
        for (int jj = 0; jj < 15; ++jj)
            d = __builtin_elementwise_fma(g1[jj], Wr[jj], d);
        gx[k] = d.x + d.y;
    }

    // ---- stores: [out(N) | h_s(4N) | h_q(N) | h_pe(4N)] ----
    dout[i] = outv;
    float4* hs = reinterpret_cast<float4*>(dout + (size_t)n);
    hs[i] = make_float4(gx[5], gx[6], gx[7], gx[8]);
    dout[(size_t)5 * n + i] = gx[4];
    float4* hpe = reinterpret_cast<float4*>(dout + (size_t)6 * n);
    hpe[i] = make_float4(gx[0], gx[1], gx[2], gx[3]);
}

extern "C" void kernel_launch(void* const* d_in, const int* in_sizes, int n_in,
                              void* d_out, int out_size, void* d_ws, size_t ws_size,
                              hipStream_t stream) {
    const int n = in_sizes[1];  // input_q has N elements
    const int blocks = (n + 255) / 256;
    hipLaunchKernelGGL(mlp_fwdbwd, dim3(blocks), dim3(256), 0, stream,
        (const float4*)d_in[0], (const float*)d_in[1], (const float4*)d_in[2],
        (const float*)d_in[3], (const float*)d_in[4],
        (const float*)d_in[5], (const float*)d_in[6],
        (const float*)d_in[7], (const float*)d_in[8],
        (const float*)d_in[9], (const float*)d_in[10],
        (float*)d_out, n);
}